// Round 9
// baseline (2671.945 us; speedup 1.0000x reference)
//
#include <hip/hip_runtime.h>
#include <math.h>

typedef unsigned short u16;
typedef unsigned int u32;
typedef __attribute__((ext_vector_type(8))) __bf16 bf16x8;
typedef __attribute__((ext_vector_type(4))) float f32x4;
typedef __attribute__((ext_vector_type(4))) _Float16 f16x4;

// ---------------- problem constants ----------------
#define MR   6144      // 48*128 rows (t-major: row = t*128 + bc)
#define KP1  320       // padded K for E=H=300
#define NPG  1280      // padded gate rows, GATE-MAJOR: row = g*320 + j
#define WSEG 409600    // u16 per weight segment [1280][320]
#define UPSEG 409600   // u16 per U perm segment [kt 10][half 2][w 4][u 10][lane 64][8]
// G perm (f16 halves): tt*163840 + s*20480 + wq*5120 + lT*256 + ln*4
#define GT_H 163840

// ---------------- workspace layout (byte offsets, 16B aligned) ----------------
#define OFF_ABF    0UL           // bf16 [6144][320]            3,932,160
#define OFF_WBF    3932160UL     // bf16 4 x [1280][320] gate-major  3,276,800
#define OFF_WCF    7208960UL     // f32  [300][1800] folded fc1 2,160,000
#define OFF_BIAS   9368960UL     // f32  4 x 1280 gate-major       20,480
#define OFF_GF     9389440UL     // f16  perm                  15,728,640
#define OFF_GR     25118080UL    // f16  perm                  15,728,640
#define OFF_HB     40846720UL    // bf16 2 dirs x [128][320]      163,840
#define OFF_VB     41010560UL    // f32  8 x [64][600]          1,228,800
#define OFF_CO     42239360UL    // f32  8 x [64][300]            614,400
#define OFF_ATT    42853760UL    // f32  3 x 48*64                 36,864
#define OFF_PT     42890624UL    // f32  [2400][64] pooled^T      614,400
#define OFF_LG     43505024UL    // f32  64*300                    76,800
#define OFF_UP     43581824UL    // bf16 4 x Uperm              3,276,800

__device__ __forceinline__ float fsig(float x) { return 1.0f / (1.0f + __expf(-x)); }
__device__ __forceinline__ float ftanh(float x) { return 1.0f - 2.0f / (__expf(2.0f * x) + 1.0f); }

__device__ __forceinline__ u16 f2bf(float x) {
    union { float f; u32 u; } v; v.f = x;
    u32 r = v.u + 0x7fffu + ((v.u >> 16) & 1u);   // RNE
    return (u16)(r >> 16);
}
__device__ __forceinline__ float bf2f(u16 x) {
    union { u32 u; float f; } v; v.u = ((u32)x) << 16; return v.f;
}

__device__ __forceinline__ void gld_lds16(const u16* g, u16* l) {
    __builtin_amdgcn_global_load_lds(
        (const __attribute__((address_space(1))) unsigned int*)g,
        (__attribute__((address_space(3))) unsigned int*)l, 16, 0, 0);
}

// ---------------- fused preprocessing ----------------
// [0,7680): emb gather -> bf16 ABF
// [7680,14080): 4 W -> gate-major bf16 [1280][320]
// [14080,20480): 4 U (fp32) -> B-fragment-major bf16 UP [kt][half][w][u][lane][8]
// [20480,20500): 4 biases -> gate-major f32 [1280]
// [20500,22610): folded fc1 weight -> f32 WCF
__global__ __launch_bounds__(256) void prep_k(
    const int* __restrict__ x1, const int* __restrict__ x2, const float* __restrict__ emb,
    const float* __restrict__ w0, const float* __restrict__ w1,
    const float* __restrict__ w2, const float* __restrict__ w3,
    const float* __restrict__ u0, const float* __restrict__ u1,
    const float* __restrict__ u2, const float* __restrict__ u3,
    const float* __restrict__ b0i, const float* __restrict__ b0h,
    const float* __restrict__ b1i, const float* __restrict__ b1h,
    const float* __restrict__ b2i, const float* __restrict__ b2h,
    const float* __restrict__ b3i, const float* __restrict__ b3h,
    const float* __restrict__ f1w,
    u16* __restrict__ abf, u16* __restrict__ wbf, u16* __restrict__ up,
    float* __restrict__ bias, float* __restrict__ wc) {
    int blk = blockIdx.x, tid = threadIdx.x;
    if (blk < 7680) {
        int idx = blk * 256 + tid;                  // MR*KP1
        int r = idx / KP1, k = idx % KP1;
        float v = 0.0f;
        if (k < 300) {
            int t = r >> 7, bc = r & 127;
            int tok = (bc < 64) ? x1[t * 64 + bc] : x2[t * 64 + bc - 64];
            v = emb[tok * 300 + k];
        }
        abf[idx] = f2bf(v);
    } else if (blk < 14080) {
        int idx = (blk - 7680) * 256 + tid;         // 4*NPG*KP1
        int s = idx / (NPG * KP1), rem = idx % (NPG * KP1);
        int r = rem / KP1, k = rem % KP1;
        const float* w = (s == 0) ? w0 : (s == 1) ? w1 : (s == 2) ? w2 : w3;
        int g = r / 320, jj = r % 320;
        float v = (jj < 300 && k < 300) ? w[(g * 300 + jj) * 300 + k] : 0.0f;
        wbf[idx] = f2bf(v);
    } else if (blk < 20480) {
        int idx = (blk - 14080) * 256 + tid;        // 4*UPSEG
        int seg = idx / UPSEG, pos = idx % UPSEG;
        int e = pos & 7, lane = (pos >> 3) & 63;
        int u = (pos >> 9) % 10;
        int w4 = (pos / 5120) % 4;
        int hf = (pos / 20480) % 2;
        int kt = pos / 40960;
        int lT = hf * 10 + u;
        int g = lT / 5, jm = lT % 5;
        int jt = w4 * 5 + jm;
        int jj = jt * 16 + (lane & 15);
        int k = kt * 32 + (lane >> 4) * 8 + e;
        const float* uu = (seg == 0) ? u0 : (seg == 1) ? u1 : (seg == 2) ? u2 : u3;
        float v = (jj < 300 && k < 300) ? uu[(g * 300 + jj) * 300 + k] : 0.0f;
        up[idx] = f2bf(v);
    } else if (blk < 20500) {
        int idx = (blk - 20480) * 256 + tid;        // 4*1280
        if (idx < 4 * NPG) {
            int s = idx / NPG, n = idx % NPG;
            int g = n / 320, jj = n % 320;
            float v = 0.0f;
            if (jj < 300) {
                int src = g * 300 + jj;
                const float* bi = (s == 0) ? b0i : (s == 1) ? b1i : (s == 2) ? b2i : b3i;
                const float* bh = (s == 0) ? b0h : (s == 1) ? b1h : (s == 2) ? b2h : b3h;
                v = bi[src] + bh[src];
            }
            bias[idx] = v;
        }
    } else {
        int idx = (blk - 20500) * 256 + tid;        // 300*1800
        if (idx < 300 * 1800) {
            int n = idx / 1800, k = idx % 1800;
            int nk = n * 2400 + k;
            float v;
            if (k < 600)       v = f1w[nk] + f1w[nk + 1800];   // c coeff: W1+W4
            else if (k < 1200) v = f1w[nk] - f1w[nk + 1200];   // a coeff: W2-W4
            else               v = f1w[nk];                    // c*a coeff: W3
            wc[idx] = v;
        }
    }
}

// ---------------- bf16 MFMA GEMM -> G in consumer-fragment-major f16 (both dirs via z) ----------------
__global__ __launch_bounds__(256) void gemm_bt2(const u16* __restrict__ A,
                                                const u16* __restrict__ Bbase,
                                                const float* __restrict__ biasbase,
                                                _Float16* __restrict__ G0,
                                                _Float16* __restrict__ G1) {
    const u16* B = Bbase + (size_t)blockIdx.z * WSEG;
    const float* bias = biasbase + (size_t)blockIdx.z * NPG;
    _Float16* Gh = blockIdx.z ? G1 : G0;
    __shared__ __align__(16) u16 smA[128 * 32];
    __shared__ __align__(16) u16 smB[128 * 32];
    int m0 = blockIdx.x * 128, n0 = blockIdx.y * 128;
    int tid = threadIdx.x, ln = tid & 63;
    int wm = (tid >> 6) & 1, wn = tid >> 7;
    int lrow = ln & 15, lq = ln >> 4;
    f32x4 acc[4][4] = {};
    for (int k0 = 0; k0 < KP1; k0 += 32) {
#pragma unroll
        for (int p = 0; p < 2; p++) {
            int e = (p * 256 + tid) * 8;
            int r = e >> 5, kk = e & 31;
            gld_lds16(A + (size_t)(m0 + r) * KP1 + k0 + kk, smA + e);
            gld_lds16(B + (size_t)(n0 + r) * KP1 + k0 + kk, smB + e);
        }
        __syncthreads();
        bf16x8 av[4], bv[4];
#pragma unroll
        for (int i = 0; i < 4; i++) {
            av[i] = *(const bf16x8*)&smA[(wm * 64 + i * 16 + lrow) * 32 + lq * 8];
            bv[i] = *(const bf16x8*)&smB[(wn * 64 + i * 16 + lrow) * 32 + lq * 8];
        }
#pragma unroll
        for (int i = 0; i < 4; i++)
#pragma unroll
            for (int j = 0; j < 4; j++)
                acc[i][j] = __builtin_amdgcn_mfma_f32_16x16x32_bf16(av[i], bv[j], acc[i][j], 0, 0, 0);
        __syncthreads();
    }
    // store to consumer layout: s = wm*4+i, T_global -> (g, jt) -> (wq, lT)
#pragma unroll
    for (int i = 0; i < 4; i++) {
        int s = wm * 4 + i;
#pragma unroll
        for (int j = 0; j < 4; j++) {
            int Tg = blockIdx.y * 8 + wn * 4 + j;
            int g = Tg / 20, jt = Tg % 20;
            int wq = jt / 5, lT = g * 5 + (jt % 5);
            int n = Tg * 16 + lrow;
            float bb = bias[n];                 // 0 for pad rows (acc also 0 there)
            f16x4 v;
#pragma unroll
            for (int r = 0; r < 4; r++) v[r] = (_Float16)(acc[i][j][r] + bb);
            *(f16x4*)(Gh + (size_t)blockIdx.x * GT_H + (size_t)s * 20480
                      + (size_t)wq * 5120 + (size_t)lT * 256 + (size_t)ln * 4) = v;
        }
    }
}

// ---------------- batch-partitioned LSTM v2: zero inter-block sync, async U streaming ----------------
// grid (8 slices, 2 dirs), block 256 = 4 waves. Each block owns 16 batch rows for all 48
// steps; h in LDS (double-buffered); c in VGPRs; U (800 KB/step, fragment-major) streamed
// L2->LDS via global_load_lds in 20 x 40KB double-buffered chunks; gates land in-lane
// (gate-major U rows) so the nonlinearity needs no LDS staging.
__global__ __launch_bounds__(256, 1) void lstm_b2(const _Float16* __restrict__ Gf,
                                                  const _Float16* __restrict__ Gr,
                                                  const u16* __restrict__ Upf,
                                                  const u16* __restrict__ Upr,
                                                  u16* __restrict__ hb) {
    int s = blockIdx.x, dir = blockIdx.y;
    const _Float16* G = dir ? Gr : Gf;
    const u16* Up = dir ? Upr : Upf;
    u16* HBp = hb + (size_t)dir * 40960;

    int tid = threadIdx.x, ln = tid & 63, w = tid >> 6;
    int lrow = ln & 15, lq = ln >> 4;

    __shared__ __align__(16) u16 Ub[2][20480];      // 2 x 40 KB U chunk double buffer
    __shared__ __align__(16) u16 h2[2][16 * 328];   // h double buffer (padded stride)

    float cst[5][4];
#pragma unroll
    for (int jm = 0; jm < 5; jm++)
#pragma unroll
        for (int r = 0; r < 4; r++) cst[jm][r] = 0.0f;

    const _Float16* Gs = G + (size_t)s * 20480 + (size_t)w * 5120 + (size_t)ln * 4;

    for (int t = 0; t < 48; t++) {
        int ttg = dir ? 47 - t : t;
        const _Float16* Gt = Gs + (size_t)ttg * GT_H;
        // G(t): issued here, consumed post-chunk-loop (overlaps the whole U stream)
        f16x4 gv[20];
#pragma unroll
        for (int lT = 0; lT < 20; lT++) gv[lT] = *(const f16x4*)(Gt + (size_t)lT * 256);

        f32x4 acc[20] = {};
        if (t > 0) {
            // h(t) A-fragments from LDS
            bf16x8 av[10];
#pragma unroll
            for (int kt = 0; kt < 10; kt++)
                av[kt] = *(const bf16x8*)&h2[t & 1][lrow * 328 + kt * 32 + lq * 8];

            // chunk pipeline: issue c+1, sync (drain c), MFMA c
            {
                const u16* src = Up;
#pragma unroll
                for (int p = 0; p < 10; p++) {
                    int e = (p * 256 + tid) * 8;
                    gld_lds16(src + e, &Ub[0][0] + e);
                }
            }
            for (int c = 0; c < 20; c++) {
                __syncthreads();                       // chunk c resident
                if (c < 19) {
                    const u16* src = Up + (size_t)(c + 1) * 20480;
                    u16* dst = &Ub[(c + 1) & 1][0];
#pragma unroll
                    for (int p = 0; p < 10; p++) {
                        int e = (p * 256 + tid) * 8;
                        gld_lds16(src + e, dst + e);
                    }
                }
                int kt = c >> 1, hf = c & 1;
#pragma unroll
                for (int u = 0; u < 10; u++) {
                    bf16x8 bv = *(const bf16x8*)&Ub[c & 1][(w * 10 + u) * 512 + ln * 8];
                    acc[hf * 10 + u] = __builtin_amdgcn_mfma_f32_16x16x32_bf16(av[kt], bv, acc[hf * 10 + u], 0, 0, 0);
                }
            }
        }

        // nonlinearity, fully in-lane: gates i,f,g,o = acc[{0,1,2,3}*5 + jm] (+ G)
#pragma unroll
        for (int jm = 0; jm < 5; jm++) {
            int j = (w * 5 + jm) * 16 + lrow;
            if (j < 300) {
#pragma unroll
                for (int r = 0; r < 4; r++) {
                    float gi = acc[jm][r]      + (float)gv[jm][r];
                    float gf = acc[5 + jm][r]  + (float)gv[5 + jm][r];
                    float gg = acc[10 + jm][r] + (float)gv[10 + jm][r];
                    float go = acc[15 + jm][r] + (float)gv[15 + jm][r];
                    float cn = fsig(gf) * cst[jm][r] + fsig(gi) * ftanh(gg);
                    float hn = fsig(go) * ftanh(cn);
                    cst[jm][r] = cn;
                    h2[(t + 1) & 1][(lq * 4 + r) * 328 + j] = f2bf(hn);
                    if (t == 47)
                        HBp[(size_t)(s * 16 + lq * 4 + r) * KP1 + j] = f2bf(hn);
                }
            }
        }
        __syncthreads();                               // h(t+1) visible block-wide
    }
}

// ---------------- fused attention prep: vbuf + attn_lite (inline enc concat) ----------------
__global__ __launch_bounds__(256) void attp_k(const u16* __restrict__ hF,
                                              const u16* __restrict__ hR,
                                              const float* __restrict__ x1m,
                                              const float* __restrict__ x2m,
                                              float* __restrict__ V,
                                              float* __restrict__ AMX,
                                              float* __restrict__ AMN,
                                              float* __restrict__ SS) {
    int tid = threadIdx.x;
    if (blockIdx.x < 150) {
        int idx = blockIdx.x * 256 + tid;
        if (idx >= 64 * 600) return;
        int b = idx / 600, d = idx % 600;
        float e1 = (d < 300) ? bf2f(hF[b * KP1 + d]) : bf2f(hR[(63 - b) * KP1 + d - 300]);
        float e2 = (d < 300) ? bf2f(hF[(64 + b) * KP1 + d]) : bf2f(hR[(127 - b) * KP1 + d - 300]);
        float p = fmaxf(e2, 0.0f), nn = fminf(e2, 0.0f);
        V[0 * 38400 + idx] = e1;
        V[1 * 38400 + idx] = p;
        V[2 * 38400 + idx] = nn;
        V[3 * 38400 + idx] = e1 * p;
        V[4 * 38400 + idx] = e1 * nn;
        V[5 * 38400 + idx] = e2;
        V[6 * 38400 + idx] = e1;
        V[7 * 38400 + idx] = e1 * e2;
        return;
    }
    int b = blockIdx.x - 150;
    __shared__ float sc[48][49];
    __shared__ float rmx[4], rmn[4];
    __shared__ float MxMn[2];
    float mx = -3.4e38f, mn = 3.4e38f;
    for (int d = tid; d < 600; d += 256) {
        float e1 = (d < 300) ? bf2f(hF[b * KP1 + d]) : bf2f(hR[(63 - b) * KP1 + d - 300]);
        float e2 = (d < 300) ? bf2f(hF[(64 + b) * KP1 + d]) : bf2f(hR[(127 - b) * KP1 + d - 300]);
        float p = e1 * e2;
        mx = fmaxf(mx, p); mn = fminf(mn, p);
    }
    for (int off = 32; off; off >>= 1) {
        mx = fmaxf(mx, __shfl_down(mx, off));
        mn = fminf(mn, __shfl_down(mn, off));
    }
    if ((tid & 63) == 0) { rmx[tid >> 6] = mx; rmn[tid >> 6] = mn; }
    __syncthreads();
    if (tid == 0) {
        MxMn[0] = fmaxf(fmaxf(rmx[0], rmx[1]), fmaxf(rmx[2], rmx[3]));
        MxMn[1] = fminf(fminf(rmn[0], rmn[1]), fminf(rmn[2], rmn[3]));
    }
    __syncthreads();
    float Mx = MxMn[0], Mn = MxMn[1];
    for (int idx = tid; idx < 2304; idx += 256) {
        int i = idx / 48, j = idx % 48;
        float q = x1m[i * 64 + b] * x2m[j * 64 + b];
        sc[i][j] = (q > 0.0f) ? q * Mx : ((q < 0.0f) ? q * Mn : 0.0f);
    }
    __syncthreads();
    if (tid < 48) {                       // alpha over axis j, row i = tid
        int i = tid;
        float m = -3.4e38f;
        for (int j = 0; j < 48; j++) m = fmaxf(m, sc[i][j]);
        float sum = 0.0f;
        for (int j = 0; j < 48; j++) sum += expf(sc[i][j] - m) * x2m[j * 64 + b];
        float wmax = -3.4e38f, wmin = 3.4e38f;
        for (int j = 0; j < 48; j++) {
            float wv = expf(sc[i][j] - m) * x2m[j * 64 + b] * x2m[j * 64 + b];
            wmax = fmaxf(wmax, wv); wmin = fminf(wmin, wv);
        }
        AMX[i * 64 + b] = wmax / sum;
        AMN[i * 64 + b] = wmin / sum;
    } else if (tid >= 64 && tid < 112) {  // beta over axis i, col j = tid-64
        int j = tid - 64;
        float m = -3.4e38f;
        for (int i = 0; i < 48; i++) m = fmaxf(m, sc[i][j]);
        float sum = 0.0f, sm = 0.0f;
        for (int i = 0; i < 48; i++) {
            float e = expf(sc[i][j] - m) * x1m[i * 64 + b];
            sum += e; sm += e * x1m[i * 64 + b];
        }
        SS[j * 64 + b] = sm / sum;
    }
}

// ---------------- 8 small fp32 GEMMs: CO[s][64][300] = V[s] @ WcSlice^T ----------------
__global__ __launch_bounds__(256) void coeff_gemm(const float* __restrict__ V,
                                                  const float* __restrict__ Wc,
                                                  float* __restrict__ CO) {
    __shared__ float As[16][64];
    __shared__ float Ws[16][64];
    int s = blockIdx.y;
    const int offs[8] = {0, 600, 600, 1200, 1200, 0, 600, 1200};
    int koff = offs[s];
    const float* A = V + (size_t)s * 38400;
    float* C = CO + (size_t)s * 19200;
    int n0 = blockIdx.x * 64;
    int tid = threadIdx.x;
    int lrow = tid >> 2;
    int lk4 = (tid & 3) << 2;
    int tm = (tid & 15) << 2;
    int tn = (tid >> 4) << 2;
    int nW = n0 + lrow;
    float acc[4][4] = {};
    for (int k0 = 0; k0 < 600; k0 += 16) {
        __syncthreads();
#pragma unroll
        for (int q = 0; q < 4; q++) {
            int k = k0 + lk4 + q;
            As[lk4 + q][lrow] = (k < 600) ? A[lrow * 600 + k] : 0.0f;
            Ws[lk4 + q][lrow] = (k < 600 && nW < 300) ? Wc[(size_t)nW * 1800 + koff + k] : 0.0f;
        }
        __syncthreads();
#pragma unroll
        for (int kk = 0; kk < 16; kk++) {
            float a0 = As[kk][tm], a1 = As[kk][tm + 1], a2 = As[kk][tm + 2], a3 = As[kk][tm + 3];
            float w0 = Ws[kk][tn], w1 = Ws[kk][tn + 1], w2 = Ws[kk][tn + 2], w3 = Ws[kk][tn + 3];
            acc[0][0] += a0 * w0; acc[0][1] += a0 * w1; acc[0][2] += a0 * w2; acc[0][3] += a0 * w3;
            acc[1][0] += a1 * w0; acc[1][1] += a1 * w1; acc[1][2] += a1 * w2; acc[1][3] += a1 * w3;
            acc[2][0] += a2 * w0; acc[2][1] += a2 * w1; acc[2][2] += a2 * w2; acc[2][3] += a2 * w3;
            acc[3][0] += a3 * w0; acc[3][1] += a3 * w1; acc[3][2] += a3 * w2; acc[3][3] += a3 * w3;
        }
    }
#pragma unroll
    for (int ii = 0; ii < 4; ii++) {
        int m = tm + ii;
#pragma unroll
        for (int jn = 0; jn < 4; jn++) {
            int n = n0 + tn + jn;
            if (n < 300) C[m * 300 + n] = acc[ii][jn];
        }
    }
}

// ---------------- rank-combine + relu -> bf16 h1 (t-major [6144][320]) ----------------
__global__ __launch_bounds__(320) void combine_k(const float* __restrict__ CO,
                                                 const float* __restrict__ f1b,
                                                 const float* __restrict__ x1m,
                                                 const float* __restrict__ x2m,
                                                 const float* __restrict__ AMX,
                                                 const float* __restrict__ AMN,
                                                 const float* __restrict__ SS,
                                                 u16* __restrict__ OUT) {
    int r = blockIdx.x;
    int t = r >> 7, bc = r & 127;
    int seq = bc >> 6, b = bc & 63;
    int n = threadIdx.x;
    if (n >= 300) return;
    int bn = b * 300 + n;
    float pre;
    if (seq == 0) {
        float m1 = x1m[t * 64 + b], am = AMX[t * 64 + b], an = AMN[t * 64 + b];
        pre = m1 * CO[bn] + am * CO[19200 + bn] + an * CO[2 * 19200 + bn]
            + m1 * am * CO[3 * 19200 + bn] + m1 * an * CO[4 * 19200 + bn] + f1b[n];
    } else {
        float m2 = x2m[t * 64 + b], sv = SS[t * 64 + b];
        pre = m2 * CO[5 * 19200 + bn] + sv * CO[6 * 19200 + bn]
            + m2 * sv * CO[7 * 19200 + bn] + f1b[n];
    }
    OUT[(size_t)r * KP1 + n] = f2bf(fmaxf(pre, 0.0f));
}

// ---------------- masked mean/max pooling (inline enc concat) -> pooled^T [2400][64] ----------------
__global__ __launch_bounds__(256) void pool_k(const u16* __restrict__ hF,
                                              const u16* __restrict__ hR,
                                              const float* __restrict__ x1m,
                                              const float* __restrict__ x2m,
                                              float* __restrict__ pooledT) {
    int idx = blockIdx.x * 256 + threadIdx.x;
    if (idx >= 64 * 2400) return;
    int b = idx / 2400, col = idx % 2400;
    int sec = col / 600, d = col % 600;
    const float* msk = (sec < 2) ? x1m : x2m;
    int bc = (sec < 2 ? 0 : 64) + b;
    int seq = bc >> 6;
    float v = (d < 300) ? bf2f(hF[bc * KP1 + d])
                        : bf2f(hR[(seq * 64 + 63 - b) * KP1 + d - 300]);
    float out;
    if ((sec & 1) == 0) {
        float s = 0, sm = 0;
        for (int t = 0; t < 48; t++) { float mv = msk[t * 64 + b]; s += v * mv; sm += mv; }
        out = s / sm;
    } else {
        float m = -3.4e38f;
        for (int t = 0; t < 48; t++) m = fmaxf(m, v * msk[t * 64 + b]);
        out = m;
    }
    pooledT[col * 64 + b] = out;
}

// ---------------- fc2 + tanh ----------------
__global__ __launch_bounds__(256) void fc2_k2(const float* __restrict__ pooledT,
                                              const float* __restrict__ f2w,
                                              const float* __restrict__ f2b,
                                              float* __restrict__ logit) {
    __shared__ float wl[2400];
    __shared__ float red[256];
    int n = blockIdx.x;
    for (int i = threadIdx.x; i < 2400; i += 256) wl[i] = f2w[n * 2400 + i];
    __syncthreads();
    int b = threadIdx.x & 63, kc = threadIdx.x >> 6;
    float acc = 0.0f;
    int k0 = kc * 600;
    for (int kk = 0; kk < 600; kk++) acc += pooledT[(k0 + kk) * 64 + b] * wl[k0 + kk];
    red[threadIdx.x] = acc;
    __syncthreads();
    if (threadIdx.x < 64) {
        float s = red[b] + red[64 + b] + red[128 + b] + red[192 + b];
        logit[b * 300 + n] = tanhf(s + f2b[n]);
    }
}

// ---------------- output layer ----------------
__global__ __launch_bounds__(64) void out_k2(const float* __restrict__ logit,
                                             const float* __restrict__ fow,
                                             const float* __restrict__ fob,
                                             float* __restrict__ out) {
    int b = blockIdx.x, tid = threadIdx.x;
    float p0 = 0, p1 = 0, p2 = 0;
    for (int k = tid; k < 300; k += 64) {
        float l = logit[b * 300 + k];
        p0 += l * fow[k]; p1 += l * fow[300 + k]; p2 += l * fow[600 + k];
    }
    for (int off = 32; off; off >>= 1) {
        p0 += __shfl_down(p0, off);
        p1 += __shfl_down(p1, off);
        p2 += __shfl_down(p2, off);
    }
    if (tid == 0) {
        out[b * 3 + 0] = p0 + fob[0];
        out[b * 3 + 1] = p1 + fob[1];
        out[b * 3 + 2] = p2 + fob[2];
    }
}

extern "C" void kernel_launch(void* const* d_in, const int* in_sizes, int n_in,
                              void* d_out, int out_size, void* d_ws, size_t ws_size,
                              hipStream_t stream) {
    (void)in_sizes; (void)n_in; (void)out_size; (void)ws_size;
    const int*   x1  = (const int*)d_in[0];
    const float* x1m = (const float*)d_in[1];
    const int*   x2  = (const int*)d_in[2];
    const float* x2m = (const float*)d_in[3];
    const float* emb = (const float*)d_in[5];
    const float* eW  = (const float*)d_in[6];
    const float* eU  = (const float*)d_in[7];
    const float* ebi = (const float*)d_in[8];
    const float* ebh = (const float*)d_in[9];
    const float* rW  = (const float*)d_in[10];
    const float* rU  = (const float*)d_in[11];
    const float* rbi = (const float*)d_in[12];
    const float* rbh = (const float*)d_in[13];
    const float* dW  = (const float*)d_in[14];
    const float* dU  = (const float*)d_in[15];
    const float* dbi = (const float*)d_in[16];
    const float* dbh = (const float*)d_in[17];
    const float* sW  = (const float*)d_in[18];
    const float* sU  = (const float*)d_in[19];
    const float* sbi = (const float*)d_in[20];
    const float* sbh = (const float*)d_in[21];
    const float* f1w = (const float*)d_in[22];
    const float* f1b = (const float*)d_in[23];
    const float* f2w = (const float*)d_in[24];
    const float* f2b = (const float*)d_in[25];
    const float* fow = (const float*)d_in[26];
    const float* fob = (const float*)d_in[27];

    char* wsb = (char*)d_ws;
    u16*       ABF  = (u16*)(wsb + OFF_ABF);
    u16*       WBF  = (u16*)(wsb + OFF_WBF);
    float*     WCF  = (float*)(wsb + OFF_WCF);
    float*     BIAS = (float*)(wsb + OFF_BIAS);
    _Float16*  GFh  = (_Float16*)(wsb + OFF_GF);
    _Float16*  GRh  = (_Float16*)(wsb + OFF_GR);
    u16*       HB   = (u16*)(wsb + OFF_HB);
    float*     VB   = (float*)(wsb + OFF_VB);
    float*     CO   = (float*)(wsb + OFF_CO);
    float*     AMX  = (float*)(wsb + OFF_ATT);
    float*     AMN  = AMX + 3072;
    float*     SS   = AMX + 6144;
    float*     PT   = (float*)(wsb + OFF_PT);
    float*     LG   = (float*)(wsb + OFF_LG);
    u16*       UP   = (u16*)(wsb + OFF_UP);

    u16* HF0 = HB;
    u16* HR0 = HB + 40960;

    // ---- fused preprocessing ----
    prep_k<<<dim3(22610), 256, 0, stream>>>(x1, x2, emb,
                                            eW, rW, dW, sW, eU, rU, dU, sU,
                                            ebi, ebh, rbi, rbh, dbi, dbh, sbi, sbh,
                                            f1w, ABF, WBF, UP, BIAS, WCF);

    // ---- encoder ----
    gemm_bt2<<<dim3(48, 10, 2), 256, 0, stream>>>(ABF, WBF, BIAS, GFh, GRh);
    lstm_b2<<<dim3(8, 2), 256, 0, stream>>>(GFh, GRh, UP, UP + UPSEG, HB);

    // ---- attention (rank-1 collapse) + fc1 ----
    attp_k<<<dim3(214), 256, 0, stream>>>(HF0, HR0, x1m, x2m, VB, AMX, AMN, SS);
    coeff_gemm<<<dim3(5, 8), 256, 0, stream>>>(VB, WCF, CO);
    combine_k<<<dim3(6144), 320, 0, stream>>>(CO, f1b, x1m, x2m, AMX, AMN, SS, ABF);

    // ---- decoder ----
    gemm_bt2<<<dim3(48, 10, 2), 256, 0, stream>>>(ABF, WBF + 2 * WSEG, BIAS + 2 * NPG, GFh, GRh);
    lstm_b2<<<dim3(8, 2), 256, 0, stream>>>(GFh, GRh, UP + 2 * UPSEG, UP + 3 * UPSEG, HB);

    // ---- pooling + classifier ----
    pool_k<<<dim3((64 * 2400 + 255) / 256), 256, 0, stream>>>(HF0, HR0, x1m, x2m, PT);
    fc2_k2<<<dim3(300), 256, 0, stream>>>(PT, f2w, f2b, LG);
    out_k2<<<dim3(64), 64, 0, stream>>>(LG, fow, fob, (float*)d_out);
}

// Round 10
// 1058.833 us; speedup vs baseline: 2.5235x; 2.5235x over previous
//
#include <hip/hip_runtime.h>
#include <math.h>

typedef unsigned short u16;
typedef unsigned int u32;
typedef unsigned long long u64;
typedef __attribute__((ext_vector_type(8))) __bf16 bf16x8;
typedef __attribute__((ext_vector_type(4))) float f32x4;
typedef __attribute__((ext_vector_type(4))) _Float16 f16x4;

// ---------------- problem constants ----------------
#define MR   6144      // 48*128 rows (t-major: row = t*128 + bc)
#define KP1  320       // padded K for E=H=300
#define NPG  1280      // padded gate rows (1200 real, interleaved 4j+g)
#define NG   1200
#define WSEG 409600    // u16 per weight segment [1280][320]
#define UPSEG 409600   // u16 per U perm segment [80 T][10 kt][64 lane][8]
// G perm (f16 halves): tt*163840 + nt*16384 + half*8192 + wm*4096 + wn*2048 + frag*256 + ln*4
#define GT_H 163840

// ---------------- workspace layout (byte offsets, 16B aligned) ----------------
#define OFF_ABF    0UL           // bf16 [6144][320]            3,932,160
#define OFF_WBF    3932160UL     // bf16 4 x [1280][320] W only 3,276,800
#define OFF_WCF    7208960UL     // f32  [300][1800] folded fc1 2,160,000
#define OFF_BIAS   9368960UL     // f32  4 x 1200 interleaved      19,200
#define OFF_GF     9388160UL     // f16  perm                  15,728,640
#define OFF_GR     25116800UL    // f16  perm                  15,728,640
#define OFF_HB     40845440UL    // bf16 2 dirs x [128][320]      163,840
#define OFF_VB     41009280UL    // f32  8 x [64][600]          1,228,800
#define OFF_CO     42238080UL    // f32  8 x [64][300]            614,400
#define OFF_ATT    42852480UL    // f32  3 x 48*64                 36,864
#define OFF_PT     42889344UL    // f32  [2400][64] pooled^T      614,400
#define OFF_LG     43503744UL    // f32  64*300                    76,800
#define OFF_UP     43580544UL    // bf16 4 x Uperm              3,276,800
#define OFF_HX     46857344UL    // bf16 2 buf x 2 dir x [128][320]  327,680
#define OFF_BAR    47185024UL    // u32  512 (2 phases x 4 groups x 64)

__device__ __forceinline__ float fsig(float x) { return 1.0f / (1.0f + __expf(-x)); }
__device__ __forceinline__ float ftanh(float x) { return 1.0f - 2.0f / (__expf(2.0f * x) + 1.0f); }

__device__ __forceinline__ u16 f2bf(float x) {
    union { float f; u32 u; } v; v.f = x;
    u32 r = v.u + 0x7fffu + ((v.u >> 16) & 1u);   // RNE
    return (u16)(r >> 16);
}
__device__ __forceinline__ float bf2f(u16 x) {
    union { u32 u; float f; } v; v.u = ((u32)x) << 16; return v.f;
}

__device__ __forceinline__ void gld_lds16(const u16* g, u16* l) {
    __builtin_amdgcn_global_load_lds(
        (const __attribute__((address_space(1))) unsigned int*)g,
        (__attribute__((address_space(3))) unsigned int*)l, 16, 0, 0);
}

// ---------------- fused preprocessing: 6 sections ----------------
// [0,7680): emb gather -> bf16 ABF
// [7680,14080): 4 W -> gate-interleaved (4j+g) bf16 [1280][320]
// [14080,20480): 4 U (fp32) -> B-fragment-major bf16 UP [seg][T][kt][lane][8]
// [20480,20499): 4 bias pairs -> interleaved f32 [4][1200]
// [20499,22609): folded fc1 weight -> f32 WCF
// [22609]: zero barrier counters
__global__ __launch_bounds__(256) void prep_k(
    const int* __restrict__ x1, const int* __restrict__ x2, const float* __restrict__ emb,
    const float* __restrict__ w0, const float* __restrict__ w1,
    const float* __restrict__ w2, const float* __restrict__ w3,
    const float* __restrict__ u0, const float* __restrict__ u1,
    const float* __restrict__ u2, const float* __restrict__ u3,
    const float* __restrict__ b0i, const float* __restrict__ b0h,
    const float* __restrict__ b1i, const float* __restrict__ b1h,
    const float* __restrict__ b2i, const float* __restrict__ b2h,
    const float* __restrict__ b3i, const float* __restrict__ b3h,
    const float* __restrict__ f1w,
    u16* __restrict__ abf, u16* __restrict__ wbf, u16* __restrict__ up,
    float* __restrict__ bias, float* __restrict__ wc, u32* __restrict__ bar) {
    int blk = blockIdx.x, tid = threadIdx.x;
    if (blk < 7680) {
        int idx = blk * 256 + tid;                  // MR*KP1
        int r = idx / KP1, k = idx % KP1;
        float v = 0.0f;
        if (k < 300) {
            int t = r >> 7, bc = r & 127;
            int tok = (bc < 64) ? x1[t * 64 + bc] : x2[t * 64 + bc - 64];
            v = emb[tok * 300 + k];
        }
        abf[idx] = f2bf(v);
    } else if (blk < 14080) {
        int idx = (blk - 7680) * 256 + tid;         // 4*NPG*KP1
        int s = idx / (NPG * KP1), rem = idx % (NPG * KP1);
        int r = rem / KP1, k = rem % KP1;
        const float* w = (s == 0) ? w0 : (s == 1) ? w1 : (s == 2) ? w2 : w3;
        float v = 0.0f;
        if (r < NG && k < 300) {
            int j = r >> 2, g = r & 3;
            v = w[(g * 300 + j) * 300 + k];
        }
        wbf[idx] = f2bf(v);
    } else if (blk < 20480) {
        int idx = (blk - 14080) * 256 + tid;        // 4*UPSEG
        int seg = idx / UPSEG, pos = idx % UPSEG;
        int T = pos / 5120, kt = (pos / 512) % 10, l = (pos >> 3) & 63, e = pos & 7;
        int n = T * 16 + (l & 15);                  // interleaved gate row 4j+g
        int k = kt * 32 + (l >> 4) * 8 + e;
        const float* u = (seg == 0) ? u0 : (seg == 1) ? u1 : (seg == 2) ? u2 : u3;
        float v = 0.0f;
        if (n < NG && k < 300) {
            int j = n >> 2, g = n & 3;
            v = u[(g * 300 + j) * 300 + k];
        }
        up[idx] = f2bf(v);
    } else if (blk < 20499) {
        int idx = (blk - 20480) * 256 + tid;        // 4*NG
        if (idx < 4 * NG) {
            int s = idx / NG, n = idx % NG;
            int j = n >> 2, g = n & 3;
            int src = g * 300 + j;
            const float* bi = (s == 0) ? b0i : (s == 1) ? b1i : (s == 2) ? b2i : b3i;
            const float* bh = (s == 0) ? b0h : (s == 1) ? b1h : (s == 2) ? b2h : b3h;
            bias[idx] = bi[src] + bh[src];
        }
    } else if (blk < 22609) {
        int idx = (blk - 20499) * 256 + tid;        // 300*1800
        if (idx < 300 * 1800) {
            int n = idx / 1800, k = idx % 1800;
            int nk = n * 2400 + k;
            float v;
            if (k < 600)       v = f1w[nk] + f1w[nk + 1800];   // c coeff: W1+W4
            else if (k < 1200) v = f1w[nk] - f1w[nk + 1200];   // a coeff: W2-W4
            else               v = f1w[nk];                    // c*a coeff: W3
            wc[idx] = v;
        }
    } else {
        bar[tid] = 0;
        bar[tid + 256] = 0;
    }
}

// ---------------- bf16 MFMA GEMM -> G in consumer-fragment-major f16 (both dirs via z) ----------------
__global__ __launch_bounds__(256) void gemm_bt2(const u16* __restrict__ A,
                                                const u16* __restrict__ Bbase,
                                                const float* __restrict__ biasbase,
                                                _Float16* __restrict__ G0,
                                                _Float16* __restrict__ G1) {
    const u16* B = Bbase + (size_t)blockIdx.z * WSEG;
    const float* bias = biasbase + (size_t)blockIdx.z * NG;
    _Float16* Gh = blockIdx.z ? G1 : G0;
    __shared__ __align__(16) u16 smA[128 * 32];
    __shared__ __align__(16) u16 smB[128 * 32];
    int m0 = blockIdx.x * 128, n0 = blockIdx.y * 128;
    int tid = threadIdx.x, ln = tid & 63;
    int wm = (tid >> 6) & 1, wn = tid >> 7;
    int lrow = ln & 15, lq = ln >> 4;
    f32x4 acc[4][4] = {};
    for (int k0 = 0; k0 < KP1; k0 += 32) {
#pragma unroll
        for (int p = 0; p < 2; p++) {
            int e = (p * 256 + tid) * 8;
            int r = e >> 5, kk = e & 31;
            gld_lds16(A + (size_t)(m0 + r) * KP1 + k0 + kk, smA + e);
            gld_lds16(B + (size_t)(n0 + r) * KP1 + k0 + kk, smB + e);
        }
        __syncthreads();
        bf16x8 av[4], bv[4];
#pragma unroll
        for (int i = 0; i < 4; i++) {
            av[i] = *(const bf16x8*)&smA[(wm * 64 + i * 16 + lrow) * 32 + lq * 8];
            bv[i] = *(const bf16x8*)&smB[(wn * 64 + i * 16 + lrow) * 32 + lq * 8];
        }
#pragma unroll
        for (int i = 0; i < 4; i++)
#pragma unroll
            for (int j = 0; j < 4; j++)
                acc[i][j] = __builtin_amdgcn_mfma_f32_16x16x32_bf16(av[i], bv[j], acc[i][j], 0, 0, 0);
        __syncthreads();
    }
    size_t tb = (size_t)blockIdx.x * GT_H + (size_t)blockIdx.y * 16384
              + (size_t)wm * 8192 + (size_t)wn * 2048 + (size_t)ln * 4;
#pragma unroll
    for (int i = 0; i < 4; i++)
#pragma unroll
        for (int j = 0; j < 4; j++) {
            int n = n0 + wn * 64 + j * 16 + lrow;
            f16x4 v;
            if (n < NG) {
                float bb = bias[n];
#pragma unroll
                for (int r = 0; r < 4; r++) v[r] = (_Float16)(acc[i][j][r] + bb);
            } else {
                v = (f16x4)0;
            }
            *(f16x4*)(Gh + tb + (size_t)(i >> 1) * 4096 + (size_t)(((i & 1) * 4 + j)) * 256) = v;
        }
}

// ---------------- LSTM (round-7 verbatim + t=0 zero-state): gate-split x half-split ----------------
// grid (10 nt, 2 dir, 2 half), block 256. U slice (80 KB) LDS-resident fragment-major;
// h exchanged via agent-scope atomics (no cache-flush fences); counter barrier per group.
__global__ __launch_bounds__(256, 1) void lstm_sync(const _Float16* __restrict__ Gf,
                                                    const _Float16* __restrict__ Gr,
                                                    const u16* __restrict__ Upf,
                                                    const u16* __restrict__ Upr,
                                                    u16* __restrict__ hx,
                                                    u16* __restrict__ hb,
                                                    u32* __restrict__ barbase) {
    int nt = blockIdx.x, dir = blockIdx.y, half = blockIdx.z;
    const _Float16* G = dir ? Gr : Gf;
    const u16* Up = dir ? Upr : Upf;
    u32* bar = barbase + (dir * 2 + half) * 64;

    int tid = threadIdx.x, ln = tid & 63, w = tid >> 6;
    int wm = w & 1, wn = w >> 1;
    int lrow = ln & 15, lq = ln >> 4;

    __shared__ __align__(16) u16 Ulds[80 * 512];    // 80 KB U slice, fragment-major
    __shared__ float P[64][132];                    // gate staging (33 KB)

    for (int p = 0; p < 20; p++) {
        int e = (p * 256 + tid) * 8;
        gld_lds16(Up + (size_t)nt * 40960 + e, Ulds + e);
    }
    __syncthreads();

    const u64* HXu = (const u64*)hx;
    u32* HXw = (u32*)hx;
    u32* HOw = (u32*)hb;

    int jp = tid & 15, bg = tid >> 4;
    bool jok = !(nt == 9 && jp >= 6);               // j0 = nt*32 + 2*jp < 300
    float c[4][2];
#pragma unroll
    for (int q = 0; q < 4; q++) { c[q][0] = 0.0f; c[q][1] = 0.0f; }

    const _Float16* Gs = G + (size_t)nt * 16384 + (size_t)half * 8192
                       + (size_t)wm * 4096 + (size_t)wn * 2048 + (size_t)ln * 4;
    f16x4 gpre[8];
    {
        int ttg = dir ? 47 : 0;
        const _Float16* Gt = Gs + (size_t)ttg * GT_H;
#pragma unroll
        for (int f = 0; f < 8; f++) gpre[f] = *(const f16x4*)(Gt + (size_t)f * 256);
    }

    for (int t = 0; t < 48; t++) {
        // ---- h(t) A-fragments via agent-coherent loads (t=0: zero state in-register) ----
        union { u64 d[2]; bf16x8 v; } hfrag[2][10];
        if (t > 0) {
            const u64* hb0 = HXu + ((size_t)(t & 1) * 2 + dir) * 10240;
#pragma unroll
            for (int i = 0; i < 2; i++) {
                int bcg = half * 64 + wm * 32 + i * 16 + lrow;
                const u64* rp = hb0 + (size_t)bcg * 80 + lq * 2;
#pragma unroll
                for (int kt = 0; kt < 10; kt++) {
                    hfrag[i][kt].d[0] = __hip_atomic_load(rp + kt * 8,     __ATOMIC_RELAXED, __HIP_MEMORY_SCOPE_AGENT);
                    hfrag[i][kt].d[1] = __hip_atomic_load(rp + kt * 8 + 1, __ATOMIC_RELAXED, __HIP_MEMORY_SCOPE_AGENT);
                }
            }
        } else {
#pragma unroll
            for (int i = 0; i < 2; i++)
#pragma unroll
                for (int kt = 0; kt < 10; kt++) { hfrag[i][kt].d[0] = 0; hfrag[i][kt].d[1] = 0; }
        }

        f32x4 acc[2][4];
#pragma unroll
        for (int i = 0; i < 2; i++)
#pragma unroll
            for (int j = 0; j < 4; j++) {
                f32x4 a;
#pragma unroll
                for (int r = 0; r < 4; r++) a[r] = (float)gpre[i * 4 + j][r];
                acc[i][j] = a;
            }

#pragma unroll
        for (int kt = 0; kt < 10; kt++) {
            bf16x8 bv[4];
#pragma unroll
            for (int j = 0; j < 4; j++)
                bv[j] = *(const bf16x8*)&Ulds[((size_t)(wn * 4 + j) * 10 + kt) * 512 + ln * 8];
#pragma unroll
            for (int i = 0; i < 2; i++)
#pragma unroll
                for (int j = 0; j < 4; j++)
                    acc[i][j] = __builtin_amdgcn_mfma_f32_16x16x32_bf16(hfrag[i][kt].v, bv[j], acc[i][j], 0, 0, 0);
        }

        // ---- stage gates to LDS ----
#pragma unroll
        for (int i = 0; i < 2; i++)
#pragma unroll
            for (int j = 0; j < 4; j++) {
                int col = wn * 64 + j * 16 + lrow;
#pragma unroll
                for (int r = 0; r < 4; r++)
                    P[wm * 32 + i * 16 + lq * 4 + r][col] = acc[i][j][r];
            }
        __syncthreads();

        // ---- prefetch next G (round-7 placement) ----
        if (t < 47) {
            int ttg = dir ? 46 - t : t + 1;
            const _Float16* Gt = Gs + (size_t)ttg * GT_H;
#pragma unroll
            for (int f = 0; f < 8; f++) gpre[f] = *(const f16x4*)(Gt + (size_t)f * 256);
        }

        // ---- nonlinearity: thread owns (bc = bg*4+q, j = nt*32 + 2*jp + {0,1}) ----
        if (jok) {
            u32* hxo = HXw + ((size_t)((t + 1) & 1) * 2 + dir) * 20480;
#pragma unroll
            for (int q = 0; q < 4; q++) {
                int bc = bg * 4 + q;
                f32x4 g0 = *(const f32x4*)&P[bc][8 * jp];
                f32x4 g1 = *(const f32x4*)&P[bc][8 * jp + 4];
                float cn0 = fsig(g0[1]) * c[q][0] + fsig(g0[0]) * ftanh(g0[2]);
                float hn0 = fsig(g0[3]) * ftanh(cn0);
                float cn1 = fsig(g1[1]) * c[q][1] + fsig(g1[0]) * ftanh(g1[2]);
                float hn1 = fsig(g1[3]) * ftanh(cn1);
                c[q][0] = cn0; c[q][1] = cn1;
                u32 pk = (u32)f2bf(hn0) | ((u32)f2bf(hn1) << 16);
                int bcg = half * 64 + bc;
                size_t oi = (size_t)bcg * 160 + nt * 16 + jp;
                if (t < 47)
                    __hip_atomic_store(hxo + oi, pk, __ATOMIC_RELAXED, __HIP_MEMORY_SCOPE_AGENT);
                else
                    HOw[(size_t)dir * 20480 + oi] = pk;
            }
        }

        if (t < 47) {
            __syncthreads();                 // per-wave vmcnt(0): h stores acked before signal
            if (tid == 0) {
                __hip_atomic_fetch_add(bar, 1u, __ATOMIC_RELAXED, __HIP_MEMORY_SCOPE_AGENT);
                u32 tgt = 10u * (u32)(t + 1);
                while (__hip_atomic_load(bar, __ATOMIC_RELAXED, __HIP_MEMORY_SCOPE_AGENT) < tgt)
                    __builtin_amdgcn_s_sleep(2);
            }
            __syncthreads();
        }
    }
}

// ---------------- fused attention prep: vbuf + attn_lite (inline enc concat) ----------------
__global__ __launch_bounds__(256) void attp_k(const u16* __restrict__ hF,
                                              const u16* __restrict__ hR,
                                              const float* __restrict__ x1m,
                                              const float* __restrict__ x2m,
                                              float* __restrict__ V,
                                              float* __restrict__ AMX,
                                              float* __restrict__ AMN,
                                              float* __restrict__ SS) {
    int tid = threadIdx.x;
    if (blockIdx.x < 150) {
        int idx = blockIdx.x * 256 + tid;
        if (idx >= 64 * 600) return;
        int b = idx / 600, d = idx % 600;
        float e1 = (d < 300) ? bf2f(hF[b * KP1 + d]) : bf2f(hR[(63 - b) * KP1 + d - 300]);
        float e2 = (d < 300) ? bf2f(hF[(64 + b) * KP1 + d]) : bf2f(hR[(127 - b) * KP1 + d - 300]);
        float p = fmaxf(e2, 0.0f), nn = fminf(e2, 0.0f);
        V[0 * 38400 + idx] = e1;
        V[1 * 38400 + idx] = p;
        V[2 * 38400 + idx] = nn;
        V[3 * 38400 + idx] = e1 * p;
        V[4 * 38400 + idx] = e1 * nn;
        V[5 * 38400 + idx] = e2;
        V[6 * 38400 + idx] = e1;
        V[7 * 38400 + idx] = e1 * e2;
        return;
    }
    int b = blockIdx.x - 150;
    __shared__ float sc[48][49];
    __shared__ float rmx[4], rmn[4];
    __shared__ float MxMn[2];
    float mx = -3.4e38f, mn = 3.4e38f;
    for (int d = tid; d < 600; d += 256) {
        float e1 = (d < 300) ? bf2f(hF[b * KP1 + d]) : bf2f(hR[(63 - b) * KP1 + d - 300]);
        float e2 = (d < 300) ? bf2f(hF[(64 + b) * KP1 + d]) : bf2f(hR[(127 - b) * KP1 + d - 300]);
        float p = e1 * e2;
        mx = fmaxf(mx, p); mn = fminf(mn, p);
    }
    for (int off = 32; off; off >>= 1) {
        mx = fmaxf(mx, __shfl_down(mx, off));
        mn = fminf(mn, __shfl_down(mn, off));
    }
    if ((tid & 63) == 0) { rmx[tid >> 6] = mx; rmn[tid >> 6] = mn; }
    __syncthreads();
    if (tid == 0) {
        MxMn[0] = fmaxf(fmaxf(rmx[0], rmx[1]), fmaxf(rmx[2], rmx[3]));
        MxMn[1] = fminf(fminf(rmn[0], rmn[1]), fminf(rmn[2], rmn[3]));
    }
    __syncthreads();
    float Mx = MxMn[0], Mn = MxMn[1];
    for (int idx = tid; idx < 2304; idx += 256) {
        int i = idx / 48, j = idx % 48;
        float q = x1m[i * 64 + b] * x2m[j * 64 + b];
        sc[i][j] = (q > 0.0f) ? q * Mx : ((q < 0.0f) ? q * Mn : 0.0f);
    }
    __syncthreads();
    if (tid < 48) {                       // alpha over axis j, row i = tid
        int i = tid;
        float m = -3.4e38f;
        for (int j = 0; j < 48; j++) m = fmaxf(m, sc[i][j]);
        float sum = 0.0f;
        for (int j = 0; j < 48; j++) sum += expf(sc[i][j] - m) * x2m[j * 64 + b];
        float wmax = -3.4e38f, wmin = 3.4e38f;
        for (int j = 0; j < 48; j++) {
            float wv = expf(sc[i][j] - m) * x2m[j * 64 + b] * x2m[j * 64 + b];
            wmax = fmaxf(wmax, wv); wmin = fminf(wmin, wv);
        }
        AMX[i * 64 + b] = wmax / sum;
        AMN[i * 64 + b] = wmin / sum;
    } else if (tid >= 64 && tid < 112) {  // beta over axis i, col j = tid-64
        int j = tid - 64;
        float m = -3.4e38f;
        for (int i = 0; i < 48; i++) m = fmaxf(m, sc[i][j]);
        float sum = 0.0f, sm = 0.0f;
        for (int i = 0; i < 48; i++) {
            float e = expf(sc[i][j] - m) * x1m[i * 64 + b];
            sum += e; sm += e * x1m[i * 64 + b];
        }
        SS[j * 64 + b] = sm / sum;
    }
}

// ---------------- 8 small fp32 GEMMs: CO[s][64][300] = V[s] @ WcSlice^T ----------------
__global__ __launch_bounds__(256) void coeff_gemm(const float* __restrict__ V,
                                                  const float* __restrict__ Wc,
                                                  float* __restrict__ CO) {
    __shared__ float As[16][64];
    __shared__ float Ws[16][64];
    int s = blockIdx.y;
    const int offs[8] = {0, 600, 600, 1200, 1200, 0, 600, 1200};
    int koff = offs[s];
    const float* A = V + (size_t)s * 38400;
    float* C = CO + (size_t)s * 19200;
    int n0 = blockIdx.x * 64;
    int tid = threadIdx.x;
    int lrow = tid >> 2;
    int lk4 = (tid & 3) << 2;
    int tm = (tid & 15) << 2;
    int tn = (tid >> 4) << 2;
    int nW = n0 + lrow;
    float acc[4][4] = {};
    for (int k0 = 0; k0 < 600; k0 += 16) {
        __syncthreads();
#pragma unroll
        for (int q = 0; q < 4; q++) {
            int k = k0 + lk4 + q;
            As[lk4 + q][lrow] = (k < 600) ? A[lrow * 600 + k] : 0.0f;
            Ws[lk4 + q][lrow] = (k < 600 && nW < 300) ? Wc[(size_t)nW * 1800 + koff + k] : 0.0f;
        }
        __syncthreads();
#pragma unroll
        for (int kk = 0; kk < 16; kk++) {
            float a0 = As[kk][tm], a1 = As[kk][tm + 1], a2 = As[kk][tm + 2], a3 = As[kk][tm + 3];
            float w0 = Ws[kk][tn], w1 = Ws[kk][tn + 1], w2 = Ws[kk][tn + 2], w3 = Ws[kk][tn + 3];
            acc[0][0] += a0 * w0; acc[0][1] += a0 * w1; acc[0][2] += a0 * w2; acc[0][3] += a0 * w3;
            acc[1][0] += a1 * w0; acc[1][1] += a1 * w1; acc[1][2] += a1 * w2; acc[1][3] += a1 * w3;
            acc[2][0] += a2 * w0; acc[2][1] += a2 * w1; acc[2][2] += a2 * w2; acc[2][3] += a2 * w3;
            acc[3][0] += a3 * w0; acc[3][1] += a3 * w1; acc[3][2] += a3 * w2; acc[3][3] += a3 * w3;
        }
    }
#pragma unroll
    for (int ii = 0; ii < 4; ii++) {
        int m = tm + ii;
#pragma unroll
        for (int jn = 0; jn < 4; jn++) {
            int n = n0 + tn + jn;
            if (n < 300) C[m * 300 + n] = acc[ii][jn];
        }
    }
}

// ---------------- rank-combine + relu -> bf16 h1 (t-major [6144][320]) ----------------
__global__ __launch_bounds__(320) void combine_k(const float* __restrict__ CO,
                                                 const float* __restrict__ f1b,
                                                 const float* __restrict__ x1m,
                                                 const float* __restrict__ x2m,
                                                 const float* __restrict__ AMX,
                                                 const float* __restrict__ AMN,
                                                 const float* __restrict__ SS,
                                                 u16* __restrict__ OUT) {
    int r = blockIdx.x;
    int t = r >> 7, bc = r & 127;
    int seq = bc >> 6, b = bc & 63;
    int n = threadIdx.x;
    if (n >= 300) return;
    int bn = b * 300 + n;
    float pre;
    if (seq == 0) {
        float m1 = x1m[t * 64 + b], am = AMX[t * 64 + b], an = AMN[t * 64 + b];
        pre = m1 * CO[bn] + am * CO[19200 + bn] + an * CO[2 * 19200 + bn]
            + m1 * am * CO[3 * 19200 + bn] + m1 * an * CO[4 * 19200 + bn] + f1b[n];
    } else {
        float m2 = x2m[t * 64 + b], sv = SS[t * 64 + b];
        pre = m2 * CO[5 * 19200 + bn] + sv * CO[6 * 19200 + bn]
            + m2 * sv * CO[7 * 19200 + bn] + f1b[n];
    }
    OUT[(size_t)r * KP1 + n] = f2bf(fmaxf(pre, 0.0f));
}

// ---------------- masked mean/max pooling (inline enc concat) -> pooled^T [2400][64] ----------------
__global__ __launch_bounds__(256) void pool_k(const u16* __restrict__ hF,
                                              const u16* __restrict__ hR,
                                              const float* __restrict__ x1m,
                                              const float* __restrict__ x2m,
                                              float* __restrict__ pooledT) {
    int idx = blockIdx.x * 256 + threadIdx.x;
    if (idx >= 64 * 2400) return;
    int b = idx / 2400, col = idx % 2400;
    int sec = col / 600, d = col % 600;
    const float* msk = (sec < 2) ? x1m : x2m;
    int bc = (sec < 2 ? 0 : 64) + b;
    int seq = bc >> 6;
    float v = (d < 300) ? bf2f(hF[bc * KP1 + d])
                        : bf2f(hR[(seq * 64 + 63 - b) * KP1 + d - 300]);
    float out;
    if ((sec & 1) == 0) {
        float s = 0, sm = 0;
        for (int t = 0; t < 48; t++) { float mv = msk[t * 64 + b]; s += v * mv; sm += mv; }
        out = s / sm;
    } else {
        float m = -3.4e38f;
        for (int t = 0; t < 48; t++) m = fmaxf(m, v * msk[t * 64 + b]);
        out = m;
    }
    pooledT[col * 64 + b] = out;
}

// ---------------- fc2 + tanh ----------------
__global__ __launch_bounds__(256) void fc2_k2(const float* __restrict__ pooledT,
                                              const float* __restrict__ f2w,
                                              const float* __restrict__ f2b,
                                              float* __restrict__ logit) {
    __shared__ float wl[2400];
    __shared__ float red[256];
    int n = blockIdx.x;
    for (int i = threadIdx.x; i < 2400; i += 256) wl[i] = f2w[n * 2400 + i];
    __syncthreads();
    int b = threadIdx.x & 63, kc = threadIdx.x >> 6;
    float acc = 0.0f;
    int k0 = kc * 600;
    for (int kk = 0; kk < 600; kk++) acc += pooledT[(k0 + kk) * 64 + b] * wl[k0 + kk];
    red[threadIdx.x] = acc;
    __syncthreads();
    if (threadIdx.x < 64) {
        float s = red[b] + red[64 + b] + red[128 + b] + red[192 + b];
        logit[b * 300 + n] = tanhf(s + f2b[n]);
    }
}

// ---------------- output layer ----------------
__global__ __launch_bounds__(64) void out_k2(const float* __restrict__ logit,
                                             const float* __restrict__ fow,
                                             const float* __restrict__ fob,
                                             float* __restrict__ out) {
    int b = blockIdx.x, tid = threadIdx.x;
    float p0 = 0, p1 = 0, p2 = 0;
    for (int k = tid; k < 300; k += 64) {
        float l = logit[b * 300 + k];
        p0 += l * fow[k]; p1 += l * fow[300 + k]; p2 += l * fow[600 + k];
    }
    for (int off = 32; off; off >>= 1) {
        p0 += __shfl_down(p0, off);
        p1 += __shfl_down(p1, off);
        p2 += __shfl_down(p2, off);
    }
    if (tid == 0) {
        out[b * 3 + 0] = p0 + fob[0];
        out[b * 3 + 1] = p1 + fob[1];
        out[b * 3 + 2] = p2 + fob[2];
    }
}

extern "C" void kernel_launch(void* const* d_in, const int* in_sizes, int n_in,
                              void* d_out, int out_size, void* d_ws, size_t ws_size,
                              hipStream_t stream) {
    (void)in_sizes; (void)n_in; (void)out_size; (void)ws_size;
    const int*   x1  = (const int*)d_in[0];
    const float* x1m = (const float*)d_in[1];
    const int*   x2  = (const int*)d_in[2];
    const float* x2m = (const float*)d_in[3];
    const float* emb = (const float*)d_in[5];
    const float* eW  = (const float*)d_in[6];
    const float* eU  = (const float*)d_in[7];
    const float* ebi = (const float*)d_in[8];
    const float* ebh = (const float*)d_in[9];
    const float* rW  = (const float*)d_in[10];
    const float* rU  = (const float*)d_in[11];
    const float* rbi = (const float*)d_in[12];
    const float* rbh = (const float*)d_in[13];
    const float* dW  = (const float*)d_in[14];
    const float* dU  = (const float*)d_in[15];
    const float* dbi = (const float*)d_in[16];
    const float* dbh = (const float*)d_in[17];
    const float* sW  = (const float*)d_in[18];
    const float* sU  = (const float*)d_in[19];
    const float* sbi = (const float*)d_in[20];
    const float* sbh = (const float*)d_in[21];
    const float* f1w = (const float*)d_in[22];
    const float* f1b = (const float*)d_in[23];
    const float* f2w = (const float*)d_in[24];
    const float* f2b = (const float*)d_in[25];
    const float* fow = (const float*)d_in[26];
    const float* fob = (const float*)d_in[27];

    char* wsb = (char*)d_ws;
    u16*       ABF  = (u16*)(wsb + OFF_ABF);
    u16*       WBF  = (u16*)(wsb + OFF_WBF);
    float*     WCF  = (float*)(wsb + OFF_WCF);
    float*     BIAS = (float*)(wsb + OFF_BIAS);
    _Float16*  GFh  = (_Float16*)(wsb + OFF_GF);
    _Float16*  GRh  = (_Float16*)(wsb + OFF_GR);
    u16*       HB   = (u16*)(wsb + OFF_HB);
    float*     VB   = (float*)(wsb + OFF_VB);
    float*     CO   = (float*)(wsb + OFF_CO);
    float*     AMX  = (float*)(wsb + OFF_ATT);
    float*     AMN  = AMX + 3072;
    float*     SS   = AMX + 6144;
    float*     PT   = (float*)(wsb + OFF_PT);
    float*     LG   = (float*)(wsb + OFF_LG);
    u16*       UP   = (u16*)(wsb + OFF_UP);
    u16*       HX   = (u16*)(wsb + OFF_HX);
    u32*       BAR  = (u32*)(wsb + OFF_BAR);

    u16* HF0 = HB;
    u16* HR0 = HB + 40960;

    // ---- fused preprocessing (incl. barrier zeroing) ----
    prep_k<<<dim3(22610), 256, 0, stream>>>(x1, x2, emb,
                                            eW, rW, dW, sW, eU, rU, dU, sU,
                                            ebi, ebh, rbi, rbh, dbi, dbh, sbi, sbh,
                                            f1w, ABF, WBF, UP, BIAS, WCF, BAR);

    // ---- encoder ----
    gemm_bt2<<<dim3(48, 10, 2), 256, 0, stream>>>(ABF, WBF, BIAS, GFh, GRh);
    lstm_sync<<<dim3(10, 2, 2), 256, 0, stream>>>(GFh, GRh, UP, UP + UPSEG, HX, HB, BAR);

    // ---- attention (rank-1 collapse) + fc1 ----
    attp_k<<<dim3(214), 256, 0, stream>>>(HF0, HR0, x1m, x2m, VB, AMX, AMN, SS);
    coeff_gemm<<<dim3(5, 8), 256, 0, stream>>>(VB, WCF, CO);
    combine_k<<<dim3(6144), 320, 0, stream>>>(CO, f1b, x1m, x2m, AMX, AMN, SS, ABF);

    // ---- decoder ----
    gemm_bt2<<<dim3(48, 10, 2), 256, 0, stream>>>(ABF, WBF + 2 * WSEG, BIAS + 2 * NG, GFh, GRh);
    lstm_sync<<<dim3(10, 2, 2), 256, 0, stream>>>(GFh, GRh, UP + 2 * UPSEG, UP + 3 * UPSEG, HX, HB, BAR + 256);

    // ---- pooling + classifier ----
    pool_k<<<dim3((64 * 2400 + 255) / 256), 256, 0, stream>>>(HF0, HR0, x1m, x2m, PT);
    fc2_k2<<<dim3(300), 256, 0, stream>>>(PT, f2w, f2b, LG);
    out_k2<<<dim3(64), 64, 0, stream>>>(LG, fow, fob, (float*)d_out);
}